// Round 3
// baseline (514.003 us; speedup 1.0000x reference)
//
#include <hip/hip_runtime.h>
#include <hip/hip_bf16.h>

// GCNConv: N=100000 nodes, E=1600000 edges, D=64.
// agg[c] = dinv[c] * ( xs[c] + sum_{e: col[e]==c} xs[row[e]] ),
//   xs[i] = (x@W)[i] * dinv[i],  dinv[i] = rsqrt(1 + indeg(i))
// out = dropout(tanh(agg + b)), JAX partitionable-threefry, key (0,42), p_keep=0.9.
// Mask bits per flat index i: threefry2x32((0,42), x0=i>>32=0, x1=i), word = o0^o1.
//
// ws layout (13.2 MB): dinv[NN] fp32 | xsh[NN*64] bf16

#define NN 100000
#define NE 1600000
#define NTOT 6400000  // NN*64

// ---------------- Threefry2x32 (JAX-exact) ----------------
__device__ __forceinline__ unsigned rotl32(unsigned x, int r) {
    return (x << r) | (x >> (32 - r));
}

__device__ __forceinline__ void threefry2x32(unsigned k0, unsigned k1,
                                             unsigned x0, unsigned x1,
                                             unsigned& o0, unsigned& o1) {
    const unsigned ks0 = k0, ks1 = k1, ks2 = k0 ^ k1 ^ 0x1BD11BDAu;
    x0 += ks0; x1 += ks1;
    x0 += x1; x1 = rotl32(x1, 13); x1 ^= x0;
    x0 += x1; x1 = rotl32(x1, 15); x1 ^= x0;
    x0 += x1; x1 = rotl32(x1, 26); x1 ^= x0;
    x0 += x1; x1 = rotl32(x1, 6);  x1 ^= x0;
    x0 += ks1; x1 += ks2 + 1u;
    x0 += x1; x1 = rotl32(x1, 17); x1 ^= x0;
    x0 += x1; x1 = rotl32(x1, 29); x1 ^= x0;
    x0 += x1; x1 = rotl32(x1, 16); x1 ^= x0;
    x0 += x1; x1 = rotl32(x1, 24); x1 ^= x0;
    x0 += ks2; x1 += ks0 + 2u;
    x0 += x1; x1 = rotl32(x1, 13); x1 ^= x0;
    x0 += x1; x1 = rotl32(x1, 15); x1 ^= x0;
    x0 += x1; x1 = rotl32(x1, 26); x1 ^= x0;
    x0 += x1; x1 = rotl32(x1, 6);  x1 ^= x0;
    x0 += ks0; x1 += ks1 + 3u;
    x0 += x1; x1 = rotl32(x1, 17); x1 ^= x0;
    x0 += x1; x1 = rotl32(x1, 29); x1 ^= x0;
    x0 += x1; x1 = rotl32(x1, 16); x1 ^= x0;
    x0 += x1; x1 = rotl32(x1, 24); x1 ^= x0;
    x0 += ks1; x1 += ks2 + 4u;
    x0 += x1; x1 = rotl32(x1, 13); x1 ^= x0;
    x0 += x1; x1 = rotl32(x1, 15); x1 ^= x0;
    x0 += x1; x1 = rotl32(x1, 26); x1 ^= x0;
    x0 += x1; x1 = rotl32(x1, 6);  x1 ^= x0;
    x0 += ks2; x1 += ks0 + 5u;
    o0 = x0; o1 = x1;
}

// ---------------- Kernels ----------------
__global__ __launch_bounds__(256) void k_deg_init(float* __restrict__ dinv) {
    int i = blockIdx.x * 256 + threadIdx.x;
    if (i < NN) dinv[i] = 1.0f;  // self-loop
}

__global__ __launch_bounds__(256) void k_deg_count(const int* __restrict__ ei,
                                                   float* __restrict__ dinv) {
    int e = blockIdx.x * 256 + threadIdx.x;
    if (e < NE) atomicAdd(&dinv[ei[NE + e]], 1.0f);  // col = targets
}

__global__ __launch_bounds__(256) void k_rsqrt(float* __restrict__ dinv) {
    int i = blockIdx.x * 256 + threadIdx.x;
    if (i < NN) dinv[i] = rsqrtf(dinv[i]);  // deg >= 1 always
}

// x@W (W staged in LDS), scale by dinv, write xsh (bf16) and init acc(=out).
__global__ __launch_bounds__(256) void k_xw(const float* __restrict__ x,
                                            const float* __restrict__ W,
                                            const float* __restrict__ dinv,
                                            __hip_bfloat16* __restrict__ xsh,
                                            float* __restrict__ acc) {
    __shared__ float Wl[64 * 64];
    __shared__ float xr[4][64];
    const int tid = threadIdx.x;
    for (int i = tid; i < 64 * 64; i += 256) Wl[i] = W[i];
    const int warp = tid >> 6, lane = tid & 63;
    const int row = blockIdx.x * 4 + warp;  // grid exact: 25000*4 == NN
    xr[warp][lane] = x[(size_t)row * 64 + lane];
    __syncthreads();
    float sum = 0.0f;
#pragma unroll
    for (int k = 0; k < 64; ++k) sum = fmaf(xr[warp][k], Wl[k * 64 + lane], sum);
    const float s = sum * dinv[row];
    xsh[(size_t)row * 64 + lane] = __float2bfloat16(s);
    acc[(size_t)row * 64 + lane] = s;  // self-loop term (dinv[c] applied at finalize)
}

// One lane per (edge, dim): acc[col] += xs[row]
__global__ __launch_bounds__(256) void k_scatter(const int* __restrict__ ei,
                                                 const __hip_bfloat16* __restrict__ xsh,
                                                 float* __restrict__ acc) {
    const long long t = (long long)blockIdx.x * 256 + threadIdx.x;
    const int e = (int)(t >> 6);
    if (e >= NE) return;
    const int d = (int)(t & 63);
    const int r = ei[e];        // source
    const int c = ei[NE + e];   // target
    atomicAdd(&acc[(size_t)c * 64 + d], __bfloat162float(xsh[(size_t)r * 64 + d]));
}

// tanh(dinv*acc + b), then JAX partitionable-threefry dropout:
// bits[i] = o0^o1 of threefry((0,42), 0, i); u = bitcast(bits>>9|0x3f800000)-1; keep = u<0.9.
__global__ __launch_bounds__(256) void k_final(const float* __restrict__ dinv,
                                               const float* __restrict__ b,
                                               float* __restrict__ out) {
    const int p = blockIdx.x * 256 + threadIdx.x;  // grid exact: 25000*256 == NTOT
    const int n = p >> 6, d = p & 63;
    unsigned o0, o1;
    threefry2x32(0u, 42u, 0u, (unsigned)p, o0, o1);
    const unsigned bits = o0 ^ o1;
    const float u = __uint_as_float((bits >> 9) | 0x3f800000u) - 1.0f;
    const float h = tanhf(dinv[n] * out[p] + b[d]);
    out[p] = (u < 0.9f) ? h / 0.9f : 0.0f;
}

extern "C" void kernel_launch(void* const* d_in, const int* in_sizes, int n_in,
                              void* d_out, int out_size, void* d_ws, size_t ws_size,
                              hipStream_t stream) {
    const float* x  = (const float*)d_in[0];
    const float* W  = (const float*)d_in[1];
    const float* b  = (const float*)d_in[2];
    const int*   ei = (const int*)d_in[3];
    float* out = (float*)d_out;

    float* dinv = (float*)d_ws;                          // [NN] fp32
    __hip_bfloat16* xsh = (__hip_bfloat16*)(dinv + NN);  // [NN*64] bf16
    float* acc = out;  // accumulate in d_out, finalize in-place

    k_deg_init<<<(NN + 255) / 256, 256, 0, stream>>>(dinv);
    k_deg_count<<<(NE + 255) / 256, 256, 0, stream>>>(ei, dinv);
    k_rsqrt<<<(NN + 255) / 256, 256, 0, stream>>>(dinv);
    k_xw<<<NN / 4, 256, 0, stream>>>(x, W, dinv, xsh, acc);
    k_scatter<<<(int)(((long long)NE * 64) / 256), 256, 0, stream>>>(ei, xsh, acc);
    k_final<<<NTOT / 256, 256, 0, stream>>>(dinv, b, out);
}

// Round 5
// 357.148 us; speedup vs baseline: 1.4392x; 1.4392x over previous
//
#include <hip/hip_runtime.h>
#include <hip/hip_bf16.h>

// GCNConv via CSR-by-target (counting sort) + per-node gather. No fp32 atomics.
// agg[c] = dinv[c] * ( xs[c] + sum_{e: col[e]==c} xs[row[e]] ),
//   xs[i] = (x@W)[i] * dinv[i],  dinv[i] = rsqrt(1 + indeg(i))
// out = dropout(tanh(agg + b)), JAX partitionable-threefry, key (0,42), p_keep=0.9:
//   bits[i] = o0^o1 of threefry((0,42), 0, i); u = bitcast(bits>>9|0x3f800000)-1; keep = u<0.9.
//
// ws layout (~20.4 MB):
//   dinv f32[NN] | xsh bf16[NN*64] | srcs i32[NE] | cnt i32[NN] | off i32[NN] | part i32[512]
// off is consumed by k_bucket (atomic bump to segment end); k_agg uses off[c]-cnt[c].

#define NN 100000
#define NE 1600000
#define NBLK 391  // ceil(NN/256)

// ---------------- Threefry2x32 (JAX-exact) ----------------
__device__ __forceinline__ unsigned rotl32(unsigned x, int r) {
    return (x << r) | (x >> (32 - r));
}

__device__ __forceinline__ void threefry2x32(unsigned k0, unsigned k1,
                                             unsigned x0, unsigned x1,
                                             unsigned& o0, unsigned& o1) {
    const unsigned ks0 = k0, ks1 = k1, ks2 = k0 ^ k1 ^ 0x1BD11BDAu;
    x0 += ks0; x1 += ks1;
    x0 += x1; x1 = rotl32(x1, 13); x1 ^= x0;
    x0 += x1; x1 = rotl32(x1, 15); x1 ^= x0;
    x0 += x1; x1 = rotl32(x1, 26); x1 ^= x0;
    x0 += x1; x1 = rotl32(x1, 6);  x1 ^= x0;
    x0 += ks1; x1 += ks2 + 1u;
    x0 += x1; x1 = rotl32(x1, 17); x1 ^= x0;
    x0 += x1; x1 = rotl32(x1, 29); x1 ^= x0;
    x0 += x1; x1 = rotl32(x1, 16); x1 ^= x0;
    x0 += x1; x1 = rotl32(x1, 24); x1 ^= x0;
    x0 += ks2; x1 += ks0 + 2u;
    x0 += x1; x1 = rotl32(x1, 13); x1 ^= x0;
    x0 += x1; x1 = rotl32(x1, 15); x1 ^= x0;
    x0 += x1; x1 = rotl32(x1, 26); x1 ^= x0;
    x0 += x1; x1 = rotl32(x1, 6);  x1 ^= x0;
    x0 += ks0; x1 += ks1 + 3u;
    x0 += x1; x1 = rotl32(x1, 17); x1 ^= x0;
    x0 += x1; x1 = rotl32(x1, 29); x1 ^= x0;
    x0 += x1; x1 = rotl32(x1, 16); x1 ^= x0;
    x0 += x1; x1 = rotl32(x1, 24); x1 ^= x0;
    x0 += ks1; x1 += ks2 + 4u;
    x0 += x1; x1 = rotl32(x1, 13); x1 ^= x0;
    x0 += x1; x1 = rotl32(x1, 15); x1 ^= x0;
    x0 += x1; x1 = rotl32(x1, 26); x1 ^= x0;
    x0 += x1; x1 = rotl32(x1, 6);  x1 ^= x0;
    x0 += ks2; x1 += ks0 + 5u;
    o0 = x0; o1 = x1;
}

// ---------------- Kernels ----------------
__global__ __launch_bounds__(256) void k_zero(int* __restrict__ cnt) {
    int i = blockIdx.x * 256 + threadIdx.x;
    if (i < NN) cnt[i] = 0;
}

__global__ __launch_bounds__(256) void k_count(const int* __restrict__ ei,
                                               int* __restrict__ cnt) {
    int e = blockIdx.x * 256 + threadIdx.x;
    if (e >= NE) return;
    const unsigned c = (unsigned)ei[NE + e];  // col = targets
    if (c < NN) atomicAdd(&cnt[c], 1);
}

// Block-level exclusive scan of cnt -> off (local), block sums -> part; also dinv.
__global__ __launch_bounds__(256) void k_scan1(const int* __restrict__ cnt,
                                               int* __restrict__ off,
                                               int* __restrict__ part,
                                               float* __restrict__ dinv) {
    __shared__ int s[256];
    const int tid = threadIdx.x;
    const int i = blockIdx.x * 256 + tid;
    const int c = (i < NN) ? cnt[i] : 0;
    s[tid] = c;
    __syncthreads();
    for (int d = 1; d < 256; d <<= 1) {
        int v = (tid >= d) ? s[tid - d] : 0;
        __syncthreads();
        s[tid] += v;
        __syncthreads();
    }
    if (i < NN) {
        off[i] = s[tid] - c;  // exclusive within block
        dinv[i] = rsqrtf(1.0f + (float)c);
    }
    if (tid == 255) part[blockIdx.x] = s[255];
}

// Scan the 391 block sums (single block of 512) -> exclusive block offsets.
__global__ __launch_bounds__(512) void k_scan2(int* __restrict__ part) {
    __shared__ int s[512];
    const int i = threadIdx.x;
    const int c = (i < NBLK) ? part[i] : 0;
    s[i] = c;
    __syncthreads();
    for (int d = 1; d < 512; d <<= 1) {
        int v = (i >= d) ? s[i - d] : 0;
        __syncthreads();
        s[i] += v;
        __syncthreads();
    }
    if (i < NBLK) part[i] = s[i] - c;  // exclusive
}

__global__ __launch_bounds__(256) void k_scan3(int* __restrict__ off,
                                               const int* __restrict__ part) {
    int i = blockIdx.x * 256 + threadIdx.x;
    if (i < NN) off[i] += part[i >> 8];
}

// Bucket edges by target: srcs[off[c]++] = row. Consumes off -> segment ends.
__global__ __launch_bounds__(256) void k_bucket(const int* __restrict__ ei,
                                                int* __restrict__ off,
                                                int* __restrict__ srcs) {
    int e = blockIdx.x * 256 + threadIdx.x;
    if (e >= NE) return;
    const int r = ei[e];
    const unsigned c = (unsigned)ei[NE + e];
    if (c >= NN) return;
    const unsigned pos = (unsigned)atomicAdd(&off[c], 1);
    if (pos < NE) srcs[pos] = r;
}

// x@W (W staged in LDS), scale by dinv, write xsh (bf16).
__global__ __launch_bounds__(256) void k_xw(const float* __restrict__ x,
                                            const float* __restrict__ W,
                                            const float* __restrict__ dinv,
                                            __hip_bfloat16* __restrict__ xsh) {
    __shared__ float Wl[64 * 64];
    __shared__ float xr[4][64];
    const int tid = threadIdx.x;
    for (int i = tid; i < 64 * 64; i += 256) Wl[i] = W[i];
    const int warp = tid >> 6, lane = tid & 63;
    const int row = blockIdx.x * 4 + warp;  // grid exact: 25000*4 == NN
    xr[warp][lane] = x[(size_t)row * 64 + lane];
    __syncthreads();
    float sum = 0.0f;
#pragma unroll
    for (int k = 0; k < 64; ++k) sum = fmaf(xr[warp][k], Wl[k * 64 + lane], sum);
    xsh[(size_t)row * 64 + lane] = __float2bfloat16(sum * dinv[row]);
}

// One wave per node: gather self + bucketed neighbors from xsh, then
// bias + tanh + JAX dropout, single write to out.
__global__ __launch_bounds__(256) void k_agg(const int* __restrict__ off,
                                             const int* __restrict__ cnt,
                                             const int* __restrict__ srcs,
                                             const __hip_bfloat16* __restrict__ xsh,
                                             const float* __restrict__ dinv,
                                             const float* __restrict__ b,
                                             float* __restrict__ out) {
    const int warp = threadIdx.x >> 6, lane = threadIdx.x & 63;
    const int c = blockIdx.x * 4 + warp;  // grid exact: 25000*4 == NN
    int num = cnt[c];
    num = (num < 0) ? 0 : (num > NE ? NE : num);  // defensive clamp (no GPU hang)
    const int start = off[c] - num;  // off[c] is segment end after k_bucket
    float acc = __bfloat162float(xsh[(size_t)c * 64 + lane]);  // self-loop
    for (int base = 0; base < num; base += 64) {
        const int m = (num - base < 64) ? (num - base) : 64;
        const int sv = (lane < m) ? srcs[start + base + lane] : 0;  // coalesced
        for (int j = 0; j < m; ++j) {
            const int s = __shfl(sv, j);
            acc += __bfloat162float(xsh[(size_t)s * 64 + lane]);
        }
    }
    const int p = c * 64 + lane;
    unsigned o0, o1;
    threefry2x32(0u, 42u, 0u, (unsigned)p, o0, o1);
    const unsigned bits = o0 ^ o1;
    const float u = __uint_as_float((bits >> 9) | 0x3f800000u) - 1.0f;
    const float h = tanhf(dinv[c] * acc + b[lane]);
    out[p] = (u < 0.9f) ? h / 0.9f : 0.0f;
}

extern "C" void kernel_launch(void* const* d_in, const int* in_sizes, int n_in,
                              void* d_out, int out_size, void* d_ws, size_t ws_size,
                              hipStream_t stream) {
    const float* x  = (const float*)d_in[0];
    const float* W  = (const float*)d_in[1];
    const float* b  = (const float*)d_in[2];
    const int*   ei = (const int*)d_in[3];
    float* out = (float*)d_out;

    float* dinv = (float*)d_ws;                          // f32[NN]
    __hip_bfloat16* xsh = (__hip_bfloat16*)(dinv + NN);  // bf16[NN*64]
    int* srcs = (int*)(xsh + (size_t)NN * 64);           // i32[NE]
    int* cnt  = srcs + NE;                               // i32[NN]
    int* off  = cnt + NN;                                // i32[NN]
    int* part = off + NN;                                // i32[512]

    k_zero<<<(NN + 255) / 256, 256, 0, stream>>>(cnt);
    k_count<<<(NE + 255) / 256, 256, 0, stream>>>(ei, cnt);
    k_scan1<<<NBLK, 256, 0, stream>>>(cnt, off, part, dinv);
    k_scan2<<<1, 512, 0, stream>>>(part);
    k_scan3<<<NBLK, 256, 0, stream>>>(off, part);
    k_bucket<<<(NE + 255) / 256, 256, 0, stream>>>(ei, off, srcs);
    k_xw<<<NN / 4, 256, 0, stream>>>(x, W, dinv, xsh);
    k_agg<<<NN / 4, 256, 0, stream>>>(off, cnt, srcs, xsh, dinv, b, out);
}